// Round 9
// baseline (651.359 us; speedup 1.0000x reference)
//
#include <hip/hip_runtime.h>
#include <math.h>

#define Hd 128
#define Ln 64
#define Bsz 8
#define NBLK 256
#define NTHR 512
#define SLOTS 32   // blocks per batch

// d_ws: T[8][64][64][128] f32 (16MB) + flags int[8][64][64] (128KB).
// Cell (b,i,j) split:
//   spec phase  : k in [1,i-2] — rows at levels <= i-2, covered by flags
//                 (i-2,j),(i-2,j+2) published one level earlier. MFMA matvec
//                 (exact 3-way bf16 split, 6 terms), Wrep B-frags in registers.
//   final phase : k=0   (wave 0: left leaf,        right T[i-1][j+1])
//                 k=i-1 (wave 1: left T[i-1][j],   right leaf)
//                 2-row f32 VALU matvec via sW (staged once), r6-proven.
// All inter-block data via agent-scope relaxed atomics (LLC-coherent).

typedef __attribute__((ext_vector_type(8))) short short8v;
typedef __attribute__((ext_vector_type(4))) float f32x4;

__global__ void init_kernel(const float* __restrict__ wf, float* __restrict__ T,
                            int* __restrict__ flg) {
    int idx = blockIdx.x * 256 + threadIdx.x;   // 0..65535
    int b = idx >> 13;
    int rest = idx & 8191;
    T[(size_t)b * (Ln * Ln * Hd) + rest] = wf[idx];
    if (idx < Bsz * Ln * Ln) flg[idx] = 0;
}

__device__ __forceinline__ float2 ld_row8(const float* p) {
    unsigned long long v = __hip_atomic_load((const unsigned long long*)p,
                                             __ATOMIC_RELAXED, __HIP_MEMORY_SCOPE_AGENT);
    return __builtin_bit_cast(float2, v);
}

__device__ __forceinline__ void wait_flag(const int* p) {
    while (__hip_atomic_load(p, __ATOMIC_RELAXED, __HIP_MEMORY_SCOPE_AGENT) == 0)
        __builtin_amdgcn_s_sleep(1);
    asm volatile("" ::: "memory");
}

// exact 3-way bf16 decomposition: x == bf(a0)+bf(a1)+bf(a2)
__device__ __forceinline__ void bf_split3(float x, unsigned short& a0,
                                          unsigned short& a1, unsigned short& a2) {
    unsigned u0 = __builtin_bit_cast(unsigned, x);
    a0 = (unsigned short)(u0 >> 16);
    float f0 = __builtin_bit_cast(float, u0 & 0xffff0000u);
    float r1 = x - f0;
    unsigned u1 = __builtin_bit_cast(unsigned, r1);
    a1 = (unsigned short)(u1 >> 16);
    float f1 = __builtin_bit_cast(float, u1 & 0xffff0000u);
    float r2 = r1 - f1;
    a2 = (unsigned short)(__builtin_bit_cast(unsigned, r2) >> 16);
}

__device__ __forceinline__ float bfval(unsigned short v) {
    return __builtin_bit_cast(float, ((unsigned)v) << 16);
}

#define KSTEP(SK, B0_, B1_, B2_)                                                \
    {                                                                           \
        int off = ((16 * ch + (ln & 15)) << 7) +                                \
                  ((((SK << 2) + (ln >> 4)) ^ (ln & 15)) << 3);                 \
        short8v a0 = *(const short8v*)&sH0[off];                                \
        short8v a1 = *(const short8v*)&sH1[off];                                \
        short8v a2 = *(const short8v*)&sH2[off];                                \
        acc = __builtin_amdgcn_mfma_f32_16x16x32_bf16(a0, B0_, acc, 0, 0, 0);   \
        acc = __builtin_amdgcn_mfma_f32_16x16x32_bf16(a0, B1_, acc, 0, 0, 0);   \
        acc = __builtin_amdgcn_mfma_f32_16x16x32_bf16(a1, B0_, acc, 0, 0, 0);   \
        acc = __builtin_amdgcn_mfma_f32_16x16x32_bf16(a0, B2_, acc, 0, 0, 0);   \
        acc = __builtin_amdgcn_mfma_f32_16x16x32_bf16(a1, B1_, acc, 0, 0, 0);   \
        acc = __builtin_amdgcn_mfma_f32_16x16x32_bf16(a2, B0_, acc, 0, 0, 0);   \
    }

// one final k-row on the VALU via f32 sW (round-6-proven pattern)
__device__ __forceinline__ void final_row(
    const float* __restrict__ lp, const float* __restrict__ rp,
    const float* __restrict__ sW, float* __restrict__ sFh,
    float* __restrict__ sFrow, float* __restrict__ sFin,
    int ln, float2 wlv, float2 wrv, float bl, float br, float bs,
    float wsA, float wsB, float bbA, float bbB)
{
    float2 L = ld_row8(lp + 2 * ln);
    float2 R = ld_row8(rp + 2 * ln);
    float pl = L.x * wlv.x + L.y * wlv.y;
    float pr = R.x * wrv.x + R.y * wrv.y;
    #pragma unroll
    for (int off2 = 32; off2 > 0; off2 >>= 1) {
        pl += __shfl_xor(pl, off2);
        pr += __shfl_xor(pr, off2);
    }
    float sl = pl + bl, sr = pr + br;
    float mm = fmaxf(sl, sr);
    float e0 = __expf(sl - mm), e1 = __expf(sr - mm);
    float inv = 1.f / (e0 + e1);
    float w0 = e0 * inv, w1 = e1 * inv;
    float2 hh;
    hh.x = w0 * L.x + w1 * R.x;
    hh.y = w0 * L.y + w1 * R.y;
    *(float2*)&sFh[2 * ln] = hh;

    const int c0 = ln, c1 = ln + 64;
    const int x0 = ln & 31;
    float a0 = 0.f, a1 = 0.f;
    const float* sW0 = &sW[c0 * Hd];
    const float* sW1 = &sW[c1 * Hd];
    #pragma unroll 8
    for (int hb = 0; hb < 32; ++hb) {
        float4 w0v = *(const float4*)&sW0[(hb ^ x0) << 2];
        float4 w1v = *(const float4*)&sW1[(hb ^ x0) << 2];
        float4 hv = *(const float4*)&sFh[hb << 2];   // broadcast
        a0 += hv.x * w0v.x + hv.y * w0v.y + hv.z * w0v.z + hv.w * w0v.w;
        a1 += hv.x * w1v.x + hv.y * w1v.y + hv.z * w1v.z + hv.w * w1v.w;
    }
    float t0 = fmaxf(a0 + bbA, 0.f) + sFh[c0];
    float t1 = fmaxf(a1 + bbB, 0.f) + sFh[c1];
    sFrow[c0] = t0;
    sFrow[c1] = t1;
    float lg = t0 * wsA + t1 * wsB;
    #pragma unroll
    for (int off2 = 32; off2 > 0; off2 >>= 1) lg += __shfl_xor(lg, off2);
    if (ln == 0) *sFin = lg + bs;
}

template<int NCH>
__device__ __forceinline__ void do_cell(
    int i, int jj, int b, int wv, int ln, int tid,
    const float* __restrict__ Tb, float* __restrict__ T, float* __restrict__ out,
    int* __restrict__ flgb,
    unsigned short* __restrict__ sH0, unsigned short* __restrict__ sH1,
    unsigned short* __restrict__ sH2,
    const float* __restrict__ sW, float* __restrict__ sFh,
    float* __restrict__ sF, float* __restrict__ sFin,
    float (*part)[Ln], float* __restrict__ sER,
    const short8v (&B0)[4], const short8v (&B1)[4], const short8v (&B2)[4],
    float2 wlv, float2 wrv, float bl, float br, float bs,
    float wsc, float bbc, float wsA, float wsB, float bbA, float bbB)
{
    const bool spec = (i >= 3);

    // ---- spec phase A: rows k in [1,i-2] (clamped duplicates elsewhere) ----
    if (spec) {
        wait_flag(&flgb[(i - 2) * Ln + jj]);
        wait_flag(&flgb[(i - 2) * Ln + jj + 2]);

        const int kmax = i - 2;
        float2 Lr[8], Rr[8];
        #pragma unroll
        for (int r = 0; r < 8; ++r) {
            int k = wv + 8 * r;
            int kcl = k < 1 ? 1 : (k > kmax ? kmax : k);
            Lr[r] = ld_row8(Tb + ((size_t)kcl * Ln + jj) * Hd + 2 * ln);
            Rr[r] = ld_row8(Tb + ((size_t)(i - 1 - kcl) * Ln + (jj + kcl + 1)) * Hd + 2 * ln);
        }
        float pl[8], pr[8];
        #pragma unroll
        for (int r = 0; r < 8; ++r) {
            pl[r] = Lr[r].x * wlv.x + Lr[r].y * wlv.y;
            pr[r] = Rr[r].x * wrv.x + Rr[r].y * wrv.y;
        }
        #pragma unroll
        for (int off2 = 32; off2 > 0; off2 >>= 1) {
            #pragma unroll
            for (int r = 0; r < 8; ++r) {
                pl[r] += __shfl_xor(pl[r], off2);
                pr[r] += __shfl_xor(pr[r], off2);
            }
        }
        #pragma unroll
        for (int r = 0; r < 8; ++r) {
            int k = wv + 8 * r;
            float sl = pl[r] + bl, sr2 = pr[r] + br;
            float mm = fmaxf(sl, sr2);
            float e0 = __expf(sl - mm), e1 = __expf(sr2 - mm);
            float inv = 1.f / (e0 + e1);
            float w0 = e0 * inv, w1 = e1 * inv;
            float h0 = w0 * Lr[r].x + w1 * Rr[r].x;
            float h1 = w0 * Lr[r].y + w1 * Rr[r].y;
            unsigned short x0s, x1s, x2s, y0s, y1s, y2s;
            bf_split3(h0, x0s, x1s, x2s);
            bf_split3(h1, y0s, y1s, y2s);
            int off = (k << 7) + (((ln >> 2) ^ (k & 15)) << 3) + ((2 * ln) & 7);
            *(unsigned*)&sH0[off] = (unsigned)x0s | ((unsigned)y0s << 16);
            *(unsigned*)&sH1[off] = (unsigned)x1s | ((unsigned)y1s << 16);
            *(unsigned*)&sH2[off] = (unsigned)x2s | ((unsigned)y2s << 16);
        }
    }
    __syncthreads();   // sH ready for MFMA

    // ---- spec MFMA matvec (or zeroed partials) ----
    const int colc = 16 * wv + (ln & 15);
    float tmp[NCH][4];
    if (spec) {
        #pragma unroll
        for (int ch = 0; ch < NCH; ++ch) {
            f32x4 acc = {0.f, 0.f, 0.f, 0.f};
            KSTEP(0, B0[0], B1[0], B2[0])
            KSTEP(1, B0[1], B1[1], B2[1])
            KSTEP(2, B0[2], B1[2], B2[2])
            KSTEP(3, B0[3], B1[3], B2[3])
            float p[4];
            #pragma unroll
            for (int q = 0; q < 4; ++q) {
                int row = 16 * ch + (ln >> 4) * 4 + q;
                int offh = (row << 7) + (((colc >> 3) ^ (row & 15)) << 3) + (colc & 7);
                float h = (bfval(sH0[offh]) + bfval(sH1[offh])) + bfval(sH2[offh]);
                float t = fmaxf(acc[q] + bbc, 0.f) + h;
                tmp[ch][q] = t;
                p[q] = t * wsc;
            }
            #pragma unroll
            for (int off2 = 1; off2 <= 8; off2 <<= 1) {
                #pragma unroll
                for (int q = 0; q < 4; ++q) p[q] += __shfl_xor(p[q], off2);
            }
            if ((ln & 15) == 0) {
                #pragma unroll
                for (int q = 0; q < 4; ++q)
                    part[wv][16 * ch + (ln >> 4) * 4 + q] = p[q];
            }
        }
    } else {
        #pragma unroll
        for (int ch = 0; ch < NCH; ++ch)
            #pragma unroll
            for (int q = 0; q < 4; ++q) tmp[ch][q] = 0.f;
    }

    // ---- final phase: fresh-flag rows on waves 0/1 ----
    if (wv == 0) {
        if (i >= 2) wait_flag(&flgb[(i - 1) * Ln + jj + 1]);
        final_row(Tb + (size_t)jj * Hd,                            // T[0][jj]
                  Tb + ((size_t)(i - 1) * Ln + (jj + 1)) * Hd,     // T[i-1][jj+1]
                  sW, sFh, sF, &sFin[0], ln,
                  wlv, wrv, bl, br, bs, wsA, wsB, bbA, bbB);
    } else if (wv == 1 && i >= 2) {
        wait_flag(&flgb[(i - 1) * Ln + jj]);
        final_row(Tb + ((size_t)(i - 1) * Ln + jj) * Hd,           // T[i-1][jj]
                  Tb + (size_t)(jj + i) * Hd,                      // T[0][jj+i]
                  sW, sFh + Hd, sF + Hd, &sFin[1], ln,
                  wlv, wrv, bl, br, bs, wsA, wsB, bbA, bbB);
    }
    __syncthreads();   // part, sF, sFin ready

    // ---- softmax over k (wave 0) ----
    if (wv == 0) {
        float lgv = -INFINITY;
        if (ln == 0) lgv = sFin[0];
        else if (ln == i - 1) lgv = sFin[1];
        else if (ln <= i - 2) {
            float ssum = part[0][ln];
            #pragma unroll
            for (int w = 1; w < 8; ++w) ssum += part[w][ln];
            lgv = ssum + bs;
        }
        float M = lgv;
        #pragma unroll
        for (int off2 = 32; off2 > 0; off2 >>= 1) M = fmaxf(M, __shfl_xor(M, off2));
        M = fmaxf(M, bs);
        float e = (ln < i) ? __expf(lgv - M) : 0.f;
        float S = e;
        #pragma unroll
        for (int off2 = 32; off2 > 0; off2 >>= 1) S += __shfl_xor(S, off2);
        float espec = (ln >= 1 && ln <= i - 2) ? e : 0.f;
        sER[ln] = espec;
        if (ln == 0) {
            sER[64] = S + (float)(Ln - i) * __expf(bs - M);
            sER[65] = e;
            if (i == 1) sER[66] = 0.f;
        }
        if (ln == i - 1 && i >= 2) sER[66] = e;
    }
    __syncthreads();   // sER ready

    // ---- weighted sum over k; add final terms; store result row ----
    float v = 0.f;
    #pragma unroll
    for (int ch = 0; ch < NCH; ++ch) {
        #pragma unroll
        for (int q = 0; q < 4; ++q)
            v += sER[16 * ch + (ln >> 4) * 4 + q] * tmp[ch][q];
    }
    v += __shfl_xor(v, 16);
    v += __shfl_xor(v, 32);
    v += sER[65] * sF[colc] + sER[66] * sF[Hd + colc];
    if (ln < 16) {
        float res = v / sER[64];
        __hip_atomic_store(&T[(((size_t)b * Ln + i) * Ln + jj) * Hd + colc], res,
                           __ATOMIC_RELAXED, __HIP_MEMORY_SCOPE_AGENT);
        if (i == Ln - 1) out[b * Hd + colc] = res;
    }
    __syncthreads();   // per-wave vmcnt(0) before s_barrier drains result stores
    if (tid == 0)
        __hip_atomic_store(&flgb[i * Ln + jj], 1, __ATOMIC_RELAXED,
                           __HIP_MEMORY_SCOPE_AGENT);
}

__global__ __launch_bounds__(NTHR, 2)
void glt_df(const float* __restrict__ Wl, const float* __restrict__ blp,
            const float* __restrict__ Wr, const float* __restrict__ brp,
            const float* __restrict__ Wrep, const float* __restrict__ brepp,
            const float* __restrict__ Wsv, const float* __restrict__ bsp,
            float* __restrict__ T, int* __restrict__ flg, float* __restrict__ out)
{
    __shared__ __align__(16) float sW[Hd * Hd];             // 64 KB f32 (final path)
    __shared__ __align__(16) unsigned short sH0[Ln * Hd];   // 16 KB
    __shared__ __align__(16) unsigned short sH1[Ln * Hd];   // 16 KB
    __shared__ __align__(16) unsigned short sH2[Ln * Hd];   // 16 KB
    __shared__ __align__(16) float sFh[2 * Hd];             // final h rows
    __shared__ __align__(16) float sF[2 * Hd];              // final t rows
    __shared__ float sFin[2];
    __shared__ float part[8][Ln];                           // 2 KB
    __shared__ float sER[68];

    const int tid = threadIdx.x;
    const int wv  = tid >> 6;
    const int ln  = tid & 63;
    const int b   = blockIdx.x & 7;      // XCD round-robin: batch -> XCD
    const int s   = blockIdx.x >> 3;     // slot 0..31 within batch

    // ---- stage sW f32 transposed+swizzled (once; conflict-free stores) ----
    #pragma unroll
    for (int it = 0; it < 8; ++it) {
        int idx4 = tid + it * NTHR;          // 0..4095
        int h  = idx4 & 127;
        int c4 = (idx4 >> 7) << 2;
        float4 v = *(const float4*)&Wrep[h * Hd + c4];
        float vv[4] = {v.x, v.y, v.z, v.w};
        #pragma unroll
        for (int q = 0; q < 4; ++q) {
            int c = c4 + q;
            sW[c * Hd + ((((h >> 2) ^ (c & 31)) << 2) | (h & 3))] = vv[q];
        }
    }

    // ---- B-fragments: Wrep cols [16wv,16wv+16) exact 3-way bf16, registers ----
    const int bcol = 16 * wv + (ln & 15);
    short8v B0[4], B1[4], B2[4];
    #pragma unroll
    for (int sk = 0; sk < 4; ++sk) {
        #pragma unroll
        for (int jx = 0; jx < 8; ++jx) {
            int k = 32 * sk + (ln >> 4) * 8 + jx;
            float w = Wrep[k * Hd + bcol];
            unsigned short w0, w1, w2;
            bf_split3(w, w0, w1, w2);
            B0[sk][jx] = (short)w0;
            B1[sk][jx] = (short)w1;
            B2[sk][jx] = (short)w2;
        }
    }

    const float bl = blp[0], br = brp[0], bs = bsp[0];
    const float2 wlv = *(const float2*)&Wl[2 * ln];
    const float2 wrv = *(const float2*)&Wr[2 * ln];
    const float wsc = Wsv[bcol], bbc = brepp[bcol];
    const float wsA = Wsv[ln], wsB = Wsv[ln + 64];
    const float bbA = brepp[ln], bbB = brepp[ln + 64];

    const float* Tb = T + (size_t)b * (Ln * Ln * Hd);
    int* flgb = flg + b * (Ln * Ln);

    // ---- level-major walk: per-batch cell index c = s + 32t, t = 0..62 ----
    int i = 1, jj = s;
    while (jj >= Ln - i) { jj -= Ln - i; ++i; }
    for (int t = 0; t < 63; ++t) {
        int nch = (i < 3) ? 1 : ((i + 14) >> 4);
        switch (nch) {
            case 1: do_cell<1>(i, jj, b, wv, ln, tid, Tb, T, out, flgb,
                               sH0, sH1, sH2, sW, sFh, sF, sFin, part, sER,
                               B0, B1, B2, wlv, wrv, bl, br, bs,
                               wsc, bbc, wsA, wsB, bbA, bbB); break;
            case 2: do_cell<2>(i, jj, b, wv, ln, tid, Tb, T, out, flgb,
                               sH0, sH1, sH2, sW, sFh, sF, sFin, part, sER,
                               B0, B1, B2, wlv, wrv, bl, br, bs,
                               wsc, bbc, wsA, wsB, bbA, bbB); break;
            case 3: do_cell<3>(i, jj, b, wv, ln, tid, Tb, T, out, flgb,
                               sH0, sH1, sH2, sW, sFh, sF, sFin, part, sER,
                               B0, B1, B2, wlv, wrv, bl, br, bs,
                               wsc, bbc, wsA, wsB, bbA, bbB); break;
            default: do_cell<4>(i, jj, b, wv, ln, tid, Tb, T, out, flgb,
                                sH0, sH1, sH2, sW, sFh, sF, sFin, part, sER,
                                B0, B1, B2, wlv, wrv, bl, br, bs,
                                wsc, bbc, wsA, wsB, bbA, bbB); break;
        }
        if (t < 62) {
            jj += SLOTS;
            while (jj >= Ln - i) { jj -= Ln - i; ++i; }
        }
    }
}

extern "C" void kernel_launch(void* const* d_in, const int* in_sizes, int n_in,
                              void* d_out, int out_size, void* d_ws, size_t ws_size,
                              hipStream_t stream)
{
    const float* wf   = (const float*)d_in[0];
    const float* Wl   = (const float*)d_in[2];
    const float* bl   = (const float*)d_in[3];
    const float* Wr   = (const float*)d_in[4];
    const float* br   = (const float*)d_in[5];
    const float* Wrep = (const float*)d_in[6];
    const float* brep = (const float*)d_in[7];
    const float* Ws   = (const float*)d_in[8];
    const float* bs   = (const float*)d_in[9];

    float* T   = (float*)d_ws;                                   // 16 MB
    int*   flg = (int*)((char*)d_ws + (size_t)Bsz * Ln * Ln * Hd * 4);
    float* out = (float*)d_out;

    init_kernel<<<256, 256, 0, stream>>>(wf, T, flg);

    void* args[] = {(void*)&Wl, (void*)&bl, (void*)&Wr, (void*)&br,
                    (void*)&Wrep, (void*)&brep, (void*)&Ws, (void*)&bs,
                    (void*)&T, (void*)&flg, (void*)&out};
    hipLaunchCooperativeKernel((void*)glt_df, dim3(NBLK), dim3(NTHR),
                               args, 0, stream);
}